// Round 7
// baseline (832.634 us; speedup 1.0000x reference)
//
#include <hip/hip_runtime.h>
#include <cstdint>
#include <cstddef>

#define E_ 8
#define T_ 1024
#define D_ 1024
#define I_ 5632
#define TWO_I_ 11264
#define NPAD_MAX 2176                 /* 2048 + 8*16 */
#define NGRP_MAX 136

// ws layout (bytes): int tables in [0,64K), then act_f, then xg_f, y overlays
// xg_f.  Packed weights live high: pb1 @ 64 MB (92.3 MB), pb2 @ 160 MB
// (46.1 MB).  Workspace is ~1.44 GB (poison fill size), so this is safe.
#define WS_ACTF_B 65536
#define WS_XGF_B  (65536 + 24510464)              /* act_f = 136*180224      */
#define WS_Y_B    WS_XGF_B                        /* y overlays dead xg_f    */
#define WS_PB1_B  67108864
#define WS_PB2_B  167772160
// int-table offsets (units of 4 B)
#define WS_CNT   0
#define WS_BASEP 8
#define WS_ESLOT 16
#define WS_TOKW  2064
#define WS_ETOK  4112

typedef __attribute__((ext_vector_type(8))) __bf16 bf16x8;
typedef __attribute__((ext_vector_type(4))) float  f32x4;

__device__ __forceinline__ unsigned f2bf(float f) {
    unsigned u = __float_as_uint(f);
    u += 0x7fffu + ((u >> 16) & 1u);
    return u >> 16;
}
__device__ __forceinline__ unsigned pack2bf(float f0, float f1) {
    unsigned a0 = __float_as_uint(f0); a0 += 0x7fffu + ((a0 >> 16) & 1u);
    unsigned a1 = __float_as_uint(f1); a1 += 0x7fffu + ((a1 >> 16) & 1u);
    return (a0 >> 16) | (a1 & 0xffff0000u);
}
#define QC(P, c) ((c) == 0 ? (P).x : (c) == 1 ? (P).y : (c) == 2 ? (P).z : (P).w)

// ---------------------------------------------------------------- routing ---
__global__ void routing_kernel(const float* __restrict__ gate,
                               int* cnt, int* basep, int* eslot,
                               float* tokw, int* etok)
{
    int t = threadIdx.x;
    if (t < E_) cnt[t] = 0;
    __syncthreads();
    float g[E_];
#pragma unroll
    for (int e = 0; e < E_; ++e) g[e] = gate[t * E_ + e];
    int i0 = 0; float p0 = g[0];
#pragma unroll
    for (int e = 1; e < E_; ++e) if (g[e] > p0) { p0 = g[e]; i0 = e; }
    int i1 = -1; float p1 = -1e30f;
#pragma unroll
    for (int e = 0; e < E_; ++e) if (e != i0 && g[e] > p1) { p1 = g[e]; i1 = e; }
    float w0 = 1.0f / (1.0f + expf(p1 - p0));
    float w1 = 1.0f - w0;
    int s0 = atomicAdd(&cnt[i0], 1);
    int s1 = atomicAdd(&cnt[i1], 1);
    etok[i0 * T_ + s0] = t;
    etok[i1 * T_ + s1] = t;
    eslot[t * 2 + 0] = i0 * T_ + s0;  tokw[t * 2 + 0] = w0;
    eslot[t * 2 + 1] = i1 * T_ + s1;  tokw[t * 2 + 1] = w1;
    __syncthreads();
    if (t == 0) {
        int r = 0;
#pragma unroll
        for (int e = 0; e < E_; ++e) { basep[e] = r; r += (cnt[e] + 15) & ~15; }
    }
}

// ------------------- gather x rows, cast bf16, fragment-major swizzle -------
__global__ void gather_cast_kernel(const float* __restrict__ x,
                                   const int* __restrict__ cnt,
                                   const int* __restrict__ basep,
                                   const int* __restrict__ etok,
                                   unsigned short* __restrict__ xgf)
{
    int e = blockIdx.x >> 6, g = blockIdx.x & 63;
    int n = cnt[e];
    if (g * 16 >= n) return;
    int tid = threadIdx.x;
    int row = g * 16 + (tid & 15);
    row = min(row, n - 1);
    int tok = etok[e * T_ + row];
    const float* xr = x + (size_t)tok * D_;
    unsigned short* dst = xgf + ((size_t)(basep[e] >> 4) + g) * 16384;
#pragma unroll
    for (int it = 0; it < 8; ++it) {
        int c = it * 16 + (tid >> 4);          // k-chunk 0..127
        float4 v0 = *(const float4*)(xr + c * 8);
        float4 v1 = *(const float4*)(xr + c * 8 + 4);
        uint4 h;
        h.x = pack2bf(v0.x, v0.y); h.y = pack2bf(v0.z, v0.w);
        h.z = pack2bf(v1.x, v1.y); h.w = pack2bf(v1.z, v1.w);
        *(uint4*)(dst + c * 128 + (tid & 15) * 8) = h;
    }
}

// ------------------------------------- repack: int32 q -> int8 (q-8) -------
// Streaming, fully coalesced: read 1-KB runs/instruction, write 1-KB runs.
// Output layout pb[e][d/8][col][8]: one MFMA cell (8 k of one col) per 8 B.
__global__ __launch_bounds__(256) void repack1_kernel(
    const int* __restrict__ w1q, char* __restrict__ pb1)
{
    int b = blockIdx.x;                 // e*1408 + dc*11 + cb
    int cb = b % 11;  int t2 = b / 11;
    int dc = t2 & 127; int e = t2 >> 7;
    int tid = threadIdx.x;
    int col = cb * 1024 + tid * 4;
    const int* src = w1q + ((size_t)e * 1024 + dc * 8) * TWO_I_ + col;
    uint4 q[8];
#pragma unroll
    for (int j = 0; j < 8; ++j)
        q[j] = *(const uint4*)(src + (size_t)j * TWO_I_);
    unsigned wo[8];
#pragma unroll
    for (int c = 0; c < 4; ++c) {
#pragma unroll
        for (int h = 0; h < 2; ++h) {
            wo[c * 2 + h] = ((QC(q[4*h+0], c) - 8u) & 255u)
                          | (((QC(q[4*h+1], c) - 8u) & 255u) << 8)
                          | (((QC(q[4*h+2], c) - 8u) & 255u) << 16)
                          | ((QC(q[4*h+3], c) - 8u) << 24);
        }
    }
    char* dst = pb1 + ((size_t)(e * 128 + dc) * TWO_I_ + col) * 8;
    *(uint4*)dst        = (uint4){wo[0], wo[1], wo[2], wo[3]};
    *(uint4*)(dst + 16) = (uint4){wo[4], wo[5], wo[6], wo[7]};
}

__global__ __launch_bounds__(256) void repack2_kernel(
    const int* __restrict__ w2q, char* __restrict__ pb2)
{
    int b = blockIdx.x;                 // e*704 + ic
    int ic = b % 704; int e = b / 704;
    int tid = threadIdx.x;
    int col = tid * 4;
    const int* src = w2q + ((size_t)e * 5632 + ic * 8) * 1024 + col;
    uint4 q[8];
#pragma unroll
    for (int j = 0; j < 8; ++j)
        q[j] = *(const uint4*)(src + (size_t)j * 1024);
    unsigned wo[8];
#pragma unroll
    for (int c = 0; c < 4; ++c) {
#pragma unroll
        for (int h = 0; h < 2; ++h) {
            wo[c * 2 + h] = ((QC(q[4*h+0], c) - 8u) & 255u)
                          | (((QC(q[4*h+1], c) - 8u) & 255u) << 8)
                          | (((QC(q[4*h+2], c) - 8u) & 255u) << 16)
                          | ((QC(q[4*h+3], c) - 8u) << 24);
        }
    }
    char* dst = pb2 + ((size_t)(e * 704 + ic) * 1024 + col) * 8;
    *(uint4*)dst        = (uint4){wo[0], wo[1], wo[2], wo[3]};
    *(uint4*)(dst + 16) = (uint4){wo[4], wo[5], wo[6], wo[7]};
}

// ------------------------------------------------- gemm1: xg@w1 + silu -----
// grid = E_*88*5, 256 thr (4 waves). Tile 64 rows x 128 B-cols (64 gate +
// 64 up), BK=64, 16 stages.  B comes from pb1 (int8 cells, L3-resident):
// per stage per thread 4x dwordx2 + byte-unpack -> one ds_write_b128 cell
// each (XOR swizzle, conflict-free both phases).  2-deep B prefetch; raw
// s_barrier + lgkmcnt(0) only; vmcnt never drained.
__global__ __launch_bounds__(256, 3) void gemm1_kernel(
    const unsigned short* __restrict__ xgf, const char* __restrict__ pb1,
    const float* __restrict__ w1s, const int* __restrict__ cnt,
    const int* __restrict__ basep, unsigned short* __restrict__ actf)
{
    __shared__ unsigned char blds[2][16384];
    int b = blockIdx.x;
    int rb = b % 5; int t2 = b / 5;
    int cg = t2 % 88; int e = t2 / 88;

    int n = cnt[e];
    if (n <= 0) return;
    int npad = (n + 15) & ~15;
    if (rb * 64 >= npad) return;
    int pb = basep[e];

    int tid = threadIdx.x, lane = tid & 63, w = tid >> 6;
    int l15 = lane & 15, lq = lane >> 4;

    // staging role: thread (colq 0..127, kh 0..1) owns 1 col x 4 cells
    int colq = tid & 127, kh = tid >> 7;
    int jb = (colq < 64) ? (cg * 64 + colq) : (I_ + cg * 64 + (colq - 64));
    const char*  bq = pb1 + ((size_t)e * 128 * TWO_I_ + jb) * 8;
    const float* sq = w1s + (size_t)e * 8 * TWO_I_ + jb;
    int fcw = colq >> 4;                       // 0..7
    int pzw = (fcw & 3) | ((fcw >> 2) << 4);
    unsigned wcell[4];
#pragma unroll
    for (int c = 0; c < 4; ++c)
        wcell[c] = (unsigned)fcw * 2048 + (unsigned)kh * 1024
                 + (unsigned)(((c * 16 + (colq & 15)) ^ pzw) << 4);

    // compute-side: wave w -> gate frag fc=w, up frag fc=w+4
    unsigned rg0 = (unsigned)w * 2048 + (unsigned)((lane ^ w) << 4);
    unsigned ru0 = (unsigned)(w + 4) * 2048 + (unsigned)((lane ^ (w | 16)) << 4);

    const char* abase = (const char*)xgf + lane * 16;

    uint2 Pa[4], Pb[4]; float Sa, Sb;

#define G1_ISSUE(S, P, SS)                                                  \
    { _Pragma("unroll")                                                     \
      for (int c_ = 0; c_ < 4; ++c_)                                        \
          P[c_] = *(const uint2*)(bq + (size_t)((S) * 8 + kh * 4 + c_) * 90112); \
      SS = sq[(size_t)((S) >> 1) * TWO_I_]; }

#define G1_DEQW(S, P, SS)                                                   \
    { unsigned char* bp_ = &blds[(S) & 1][0];                               \
      _Pragma("unroll")                                                     \
      for (int c_ = 0; c_ < 4; ++c_) {                                      \
          unsigned px_ = P[c_].x, py_ = P[c_].y;                            \
          float f0_ = (float)(int)(char)(px_);                              \
          float f1_ = (float)(int)(char)(px_ >> 8);                         \
          float f2_ = (float)(int)(char)(px_ >> 16);                        \
          float f3_ = (float)((int)px_ >> 24);                              \
          float f4_ = (float)(int)(char)(py_);                              \
          float f5_ = (float)(int)(char)(py_ >> 8);                         \
          float f6_ = (float)(int)(char)(py_ >> 16);                        \
          float f7_ = (float)((int)py_ >> 24);                              \
          uint4 h_;                                                         \
          h_.x = pack2bf(f0_ * SS, f1_ * SS);                               \
          h_.y = pack2bf(f2_ * SS, f3_ * SS);                               \
          h_.z = pack2bf(f4_ * SS, f5_ * SS);                               \
          h_.w = pack2bf(f6_ * SS, f7_ * SS);                               \
          *(uint4*)(bp_ + wcell[c_]) = h_;                                  \
      } }

    for (int tb = rb * 64; tb < npad; tb += 320) {
        int aoff[4];
#pragma unroll
        for (int mi = 0; mi < 4; ++mi) {
            int R = tb + mi * 16;
            R = min(R, npad - 16);
            aoff[mi] = ((pb + R) >> 4) * 32768;
        }
        f32x4 accg[4], accu[4];
#pragma unroll
        for (int mi = 0; mi < 4; ++mi) {
            accg[mi] = (f32x4){0.f, 0.f, 0.f, 0.f};
            accu[mi] = (f32x4){0.f, 0.f, 0.f, 0.f};
        }

        G1_ISSUE(0, Pa, Sa)
        G1_ISSUE(1, Pb, Sb)
        G1_DEQW(0, Pa, Sa)
        asm volatile("s_waitcnt lgkmcnt(0)" ::: "memory");
        __builtin_amdgcn_s_barrier();
        asm volatile("" ::: "memory");

#pragma unroll 2
        for (int st = 0; st < 16; ++st) {
            const char* at = abase + (size_t)st * 2048;
            bf16x8 a0[4], a1[4];
#pragma unroll
            for (int mi = 0; mi < 4; ++mi)
                a0[mi] = *(const bf16x8*)(at + aoff[mi]);
#pragma unroll
            for (int mi = 0; mi < 4; ++mi)
                a1[mi] = *(const bf16x8*)(at + 1024 + aoff[mi]);
            if (st + 2 < 16) {
                if (st & 1) { G1_ISSUE(st + 2, Pb, Sb) }
                else        { G1_ISSUE(st + 2, Pa, Sa) }
            }
            const unsigned char* bp = &blds[st & 1][0];
            bf16x8 bg0 = *(const bf16x8*)(bp + rg0);
            bf16x8 bu0 = *(const bf16x8*)(bp + ru0);
            bf16x8 bg1 = *(const bf16x8*)(bp + rg0 + 1024);
            bf16x8 bu1 = *(const bf16x8*)(bp + ru0 + 1024);
            __builtin_amdgcn_s_setprio(1);
#pragma unroll
            for (int mi = 0; mi < 4; ++mi) {
                accg[mi] = __builtin_amdgcn_mfma_f32_16x16x32_bf16(a0[mi], bg0, accg[mi], 0, 0, 0);
                accu[mi] = __builtin_amdgcn_mfma_f32_16x16x32_bf16(a0[mi], bu0, accu[mi], 0, 0, 0);
            }
#pragma unroll
            for (int mi = 0; mi < 4; ++mi) {
                accg[mi] = __builtin_amdgcn_mfma_f32_16x16x32_bf16(a1[mi], bg1, accg[mi], 0, 0, 0);
                accu[mi] = __builtin_amdgcn_mfma_f32_16x16x32_bf16(a1[mi], bu1, accu[mi], 0, 0, 0);
            }
            __builtin_amdgcn_s_setprio(0);
            if (st + 1 < 16) {
                if (st & 1) { G1_DEQW(st + 1, Pa, Sa) }
                else        { G1_DEQW(st + 1, Pb, Sb) }
            }
            asm volatile("s_waitcnt lgkmcnt(0)" ::: "memory");
            __builtin_amdgcn_s_barrier();
            asm volatile("" ::: "memory");
        }

        // epilogue: silu(gate)*up -> act_f fragment-major
#pragma unroll
        for (int mi = 0; mi < 4; ++mi) {
#pragma unroll
            for (int r = 0; r < 4; ++r) {
                int m = tb + mi * 16 + lq * 4 + r;
                if (m < npad) {
                    float gv = accg[mi][r], uv = accu[mi][r];
                    float av = gv / (1.f + __expf(-gv)) * uv;
                    int prow = pb + m;
                    int icol = cg * 64 + w * 16 + l15;
                    size_t o = (size_t)(prow >> 4) * 90112 + (icol >> 3) * 128
                             + (prow & 15) * 8 + (icol & 7);
                    actf[o] = (unsigned short)f2bf(av);
                }
            }
        }
    }
#undef G1_ISSUE
#undef G1_DEQW
}

// ---------------------------------------------------- gemm2: act@w2 --------
// grid = E_*8dt*4seg*5rb = 1280, 256 thr. Tile 64 rows x 128 cols, K/seg =
// 1408 (22 stages of BK=64). B from pb2 (int8 cells, L3-resident).
__global__ __launch_bounds__(256, 3) void gemm2_kernel(
    const unsigned short* __restrict__ actf, const char* __restrict__ pb2,
    const float* __restrict__ w2s, const int* __restrict__ cnt,
    const int* __restrict__ basep, float* __restrict__ y)
{
    __shared__ unsigned char blds[2][16384];
    int b = blockIdx.x;
    int rb = b % 5; int t2 = b / 5;
    int seg = t2 & 3, dt = (t2 >> 2) & 7, e = t2 >> 5;

    int n = cnt[e];
    if (n <= 0) return;
    int npad = (n + 15) & ~15;
    if (rb * 64 >= npad) return;
    int pb = basep[e];

    int tid = threadIdx.x, lane = tid & 63, w = tid >> 6;
    int l15 = lane & 15, lq = lane >> 4;

    int colq = tid & 127, kh = tid >> 7;
    int dcol = dt * 128 + colq;
    const char*  bq = pb2 + ((size_t)(e * 704 + seg * 176) * 1024 + dcol) * 8;
    const float* sq = w2s + ((size_t)e * 44 + seg * 11) * 1024 + dcol;
    int fcw = colq >> 4;
    int pzw = (fcw & 3) | ((fcw >> 2) << 4);
    unsigned wcell[4];
#pragma unroll
    for (int c = 0; c < 4; ++c)
        wcell[c] = (unsigned)fcw * 2048 + (unsigned)kh * 1024
                 + (unsigned)(((c * 16 + (colq & 15)) ^ pzw) << 4);

    unsigned rg0 = (unsigned)w * 2048 + (unsigned)((lane ^ w) << 4);
    unsigned ru0 = (unsigned)(w + 4) * 2048 + (unsigned)((lane ^ (w | 16)) << 4);

    const char* abase = (const char*)actf + seg * 45056 + lane * 16;

    uint2 Pa[4], Pb[4]; float Sa, Sb;

#define G2_ISSUE(S, P, SS)                                                  \
    { _Pragma("unroll")                                                     \
      for (int c_ = 0; c_ < 4; ++c_)                                        \
          P[c_] = *(const uint2*)(bq + (size_t)((S) * 8 + kh * 4 + c_) * 8192); \
      SS = sq[(size_t)((S) >> 1) * 1024]; }

#define G2_DEQW(S, P, SS)                                                   \
    { unsigned char* bp_ = &blds[(S) & 1][0];                               \
      _Pragma("unroll")                                                     \
      for (int c_ = 0; c_ < 4; ++c_) {                                      \
          unsigned px_ = P[c_].x, py_ = P[c_].y;                            \
          float f0_ = (float)(int)(char)(px_);                              \
          float f1_ = (float)(int)(char)(px_ >> 8);                         \
          float f2_ = (float)(int)(char)(px_ >> 16);                        \
          float f3_ = (float)((int)px_ >> 24);                              \
          float f4_ = (float)(int)(char)(py_);                              \
          float f5_ = (float)(int)(char)(py_ >> 8);                         \
          float f6_ = (float)(int)(char)(py_ >> 16);                        \
          float f7_ = (float)((int)py_ >> 24);                              \
          uint4 h_;                                                         \
          h_.x = pack2bf(f0_ * SS, f1_ * SS);                               \
          h_.y = pack2bf(f2_ * SS, f3_ * SS);                               \
          h_.z = pack2bf(f4_ * SS, f5_ * SS);                               \
          h_.w = pack2bf(f6_ * SS, f7_ * SS);                               \
          *(uint4*)(bp_ + wcell[c_]) = h_;                                  \
      } }

    for (int tb = rb * 64; tb < npad; tb += 320) {
        int aoff[4];
#pragma unroll
        for (int mi = 0; mi < 4; ++mi) {
            int R = tb + mi * 16;
            R = min(R, npad - 16);
            aoff[mi] = ((pb + R) >> 4) * 180224;
        }
        f32x4 acc0[4], acc1[4];
#pragma unroll
        for (int mi = 0; mi < 4; ++mi) {
            acc0[mi] = (f32x4){0.f, 0.f, 0.f, 0.f};
            acc1[mi] = (f32x4){0.f, 0.f, 0.f, 0.f};
        }

        G2_ISSUE(0, Pa, Sa)
        G2_ISSUE(1, Pb, Sb)
        G2_DEQW(0, Pa, Sa)
        asm volatile("s_waitcnt lgkmcnt(0)" ::: "memory");
        __builtin_amdgcn_s_barrier();
        asm volatile("" ::: "memory");

#pragma unroll 2
        for (int st = 0; st < 22; ++st) {
            const char* at = abase + (size_t)st * 2048;
            bf16x8 a0[4], a1[4];
#pragma unroll
            for (int mi = 0; mi < 4; ++mi)
                a0[mi] = *(const bf16x8*)(at + aoff[mi]);
#pragma unroll
            for (int mi = 0; mi < 4; ++mi)
                a1[mi] = *(const bf16x8*)(at + 1024 + aoff[mi]);
            if (st + 2 < 22) {
                if (st & 1) { G2_ISSUE(st + 2, Pb, Sb) }
                else        { G2_ISSUE(st + 2, Pa, Sa) }
            }
            const unsigned char* bp = &blds[st & 1][0];
            bf16x8 b00 = *(const bf16x8*)(bp + rg0);
            bf16x8 b10 = *(const bf16x8*)(bp + ru0);
            bf16x8 b01 = *(const bf16x8*)(bp + rg0 + 1024);
            bf16x8 b11 = *(const bf16x8*)(bp + ru0 + 1024);
            __builtin_amdgcn_s_setprio(1);
#pragma unroll
            for (int mi = 0; mi < 4; ++mi) {
                acc0[mi] = __builtin_amdgcn_mfma_f32_16x16x32_bf16(a0[mi], b00, acc0[mi], 0, 0, 0);
                acc1[mi] = __builtin_amdgcn_mfma_f32_16x16x32_bf16(a0[mi], b10, acc1[mi], 0, 0, 0);
            }
#pragma unroll
            for (int mi = 0; mi < 4; ++mi) {
                acc0[mi] = __builtin_amdgcn_mfma_f32_16x16x32_bf16(a1[mi], b01, acc0[mi], 0, 0, 0);
                acc1[mi] = __builtin_amdgcn_mfma_f32_16x16x32_bf16(a1[mi], b11, acc1[mi], 0, 0, 0);
            }
            __builtin_amdgcn_s_setprio(0);
            if (st + 1 < 22) {
                if (st & 1) { G2_DEQW(st + 1, Pa, Sa) }
                else        { G2_DEQW(st + 1, Pb, Sb) }
            }
            asm volatile("s_waitcnt lgkmcnt(0)" ::: "memory");
            __builtin_amdgcn_s_barrier();
            asm volatile("" ::: "memory");
        }

#pragma unroll
        for (int mi = 0; mi < 4; ++mi) {
#pragma unroll
            for (int r = 0; r < 4; ++r) {
                int m = tb + mi * 16 + lq * 4 + r;
                if (m < n) {
                    float* yr = y + ((size_t)seg * NPAD_MAX + pb + m) * 1024;
                    int dc = dt * 128 + w * 16 + l15;
                    yr[dc]      = acc0[mi][r];
                    yr[dc + 64] = acc1[mi][r];
                }
            }
        }
    }
#undef G2_ISSUE
#undef G2_DEQW
}

// --------------------------------------------------------------- combine ---
__global__ void combine_kernel(const float* __restrict__ y,
                               const int* __restrict__ eslot,
                               const float* __restrict__ tokw,
                               const int* __restrict__ basep,
                               float* __restrict__ out)
{
    int idx = blockIdx.x * blockDim.x + threadIdx.x;
    int t  = idx >> 8;
    int dc = idx & 255;
    int es0 = eslot[t * 2 + 0], es1 = eslot[t * 2 + 1];
    float w0 = tokw[t * 2 + 0], w1 = tokw[t * 2 + 1];
    int p0 = basep[es0 >> 10] + (es0 & 1023);
    int p1 = basep[es1 >> 10] + (es1 & 1023);
    const float4* y4 = (const float4*)y;
    float4 o = (float4){0.f, 0.f, 0.f, 0.f};
#pragma unroll
    for (int seg = 0; seg < 4; ++seg) {
        float4 a = y4[((size_t)seg * NPAD_MAX + p0) * 256 + dc];
        float4 b = y4[((size_t)seg * NPAD_MAX + p1) * 256 + dc];
        o.x += w0 * a.x + w1 * b.x;
        o.y += w0 * a.y + w1 * b.y;
        o.z += w0 * a.z + w1 * b.z;
        o.w += w0 * a.w + w1 * b.w;
    }
    ((float4*)out)[idx] = o;
}

// ---------------------------------------------------------------- launch ---
extern "C" void kernel_launch(void* const* d_in, const int* in_sizes, int n_in,
                              void* d_out, int out_size, void* d_ws, size_t ws_size,
                              hipStream_t stream)
{
    const float* x    = (const float*)d_in[0];
    const float* gate = (const float*)d_in[1];
    const int*   w1q  = (const int*)d_in[2];
    const int*   w2q  = (const int*)d_in[3];
    const float* w1s  = (const float*)d_in[4];
    const float* w2s  = (const float*)d_in[5];
    float* out = (float*)d_out;
    int*   wsi = (int*)d_ws;
    float* wsf = (float*)d_ws;

    int*   cnt   = wsi + WS_CNT;
    int*   basep = wsi + WS_BASEP;
    int*   eslot = wsi + WS_ESLOT;
    float* tokw  = wsf + WS_TOKW;
    int*   etok  = wsi + WS_ETOK;
    unsigned short* actf = (unsigned short*)((char*)d_ws + WS_ACTF_B);
    unsigned short* xgf  = (unsigned short*)((char*)d_ws + WS_XGF_B);
    float*          y    = (float*)((char*)d_ws + WS_Y_B);
    char*           pb1  = (char*)d_ws + WS_PB1_B;
    char*           pb2  = (char*)d_ws + WS_PB2_B;

    routing_kernel<<<1, 1024, 0, stream>>>(gate, cnt, basep, eslot, tokw, etok);
    gather_cast_kernel<<<E_ * 64, 256, 0, stream>>>(x, cnt, basep, etok, xgf);
    repack1_kernel<<<E_ * 128 * 11, 256, 0, stream>>>(w1q, pb1);
    repack2_kernel<<<E_ * 704, 256, 0, stream>>>(w2q, pb2);
    gemm1_kernel<<<E_ * 88 * 5, 256, 0, stream>>>(xgf, pb1, w1s, cnt, basep, actf);
    gemm2_kernel<<<E_ * 8 * 4 * 5, 256, 0, stream>>>(actf, pb2, w2s, cnt, basep, y);
    combine_kernel<<<(T_ * D_ / 4) / 256, 256, 0, stream>>>(y, eslot, tokw, basep, out);
}